// Round 16
// baseline (489.312 us; speedup 1.0000x reference)
//
#include <hip/hip_runtime.h>
#include <hip/hip_bf16.h>

#define DIM 2048
#define HEAD_DIM 128
#define N_HEADS 16
#define SEQ 2048
#define HID 8192
#define SQKV 6144   // row stride of fused qkv activation

typedef short bf16x8 __attribute__((ext_vector_type(8)));
typedef float f32x4 __attribute__((ext_vector_type(4)));
typedef float f32x16 __attribute__((ext_vector_type(16)));
using bf16 = __hip_bfloat16;

#define MFMA16(a, b, c) __builtin_amdgcn_mfma_f32_16x16x32_bf16(a, b, c, 0, 0, 0)
#define MFMA32(a, b, c) __builtin_amdgcn_mfma_f32_32x32x16_bf16(a, b, c, 0, 0, 0)

__device__ __forceinline__ unsigned short f2bu(float f) {
    union { bf16 b; unsigned short u; } cv;
    cv.b = __float2bfloat16(f);
    return cv.u;
}
__device__ __forceinline__ float bu2f(unsigned short u) {
    union { unsigned short u; bf16 b; } cv;
    cv.u = u;
    return __bfloat162float(cv.b);
}

// async global -> LDS, 16B per lane (dest must be lane-linear per wave)
__device__ __forceinline__ void gl16(const void* g, void* l) {
    __builtin_amdgcn_global_load_lds(
        (const __attribute__((address_space(1))) unsigned int*)g,
        (__attribute__((address_space(3))) unsigned int*)l, 16, 0, 0);
}

// ---------------- rmsnorm (fp32 in -> bf16 out) ----------------
__global__ __launch_bounds__(256) void rmsnorm_bf16_k(
    const float* __restrict__ x, const float* __restrict__ w, bf16* __restrict__ y)
{
    const int row = blockIdx.x;
    const int tid = threadIdx.x;
    const float* xr = x + (size_t)row * DIM;
    float4 v0 = ((const float4*)xr)[tid];
    float4 v1 = ((const float4*)xr)[tid + 256];
    float ss = v0.x*v0.x + v0.y*v0.y + v0.z*v0.z + v0.w*v0.w
             + v1.x*v1.x + v1.y*v1.y + v1.z*v1.z + v1.w*v1.w;
    for (int o = 32; o > 0; o >>= 1) ss += __shfl_down(ss, o);
    __shared__ float red[4];
    if ((tid & 63) == 0) red[tid >> 6] = ss;
    __syncthreads();
    float tot = red[0] + red[1] + red[2] + red[3];
    float r = rsqrtf(tot * (1.0f / DIM) + 1e-6f);
    float4 w0 = ((const float4*)w)[tid];
    float4 w1 = ((const float4*)w)[tid + 256];
    ushort4 o0, o1;
    o0.x = f2bu(v0.x * r * w0.x); o0.y = f2bu(v0.y * r * w0.y);
    o0.z = f2bu(v0.z * r * w0.z); o0.w = f2bu(v0.w * r * w0.w);
    o1.x = f2bu(v1.x * r * w1.x); o1.y = f2bu(v1.y * r * w1.y);
    o1.z = f2bu(v1.z * r * w1.z); o1.w = f2bu(v1.w * r * w1.w);
    ushort4* yr = (ushort4*)(y + (size_t)row * DIM);
    yr[tid] = o0;
    yr[tid + 256] = o1;
}

// ---------------- split-K(bf16) reduce + residual + rmsnorm (fp32 h out, bf16 fn out) ----------------
__global__ __launch_bounds__(256) void rmsnorm4_k(
    const bf16* __restrict__ part, const float* __restrict__ x,
    const float* __restrict__ w, float* __restrict__ hout, bf16* __restrict__ y)
{
    const int row = blockIdx.x;
    const int tid = threadIdx.x;
    const size_t base = (size_t)row * DIM + tid * 8;
    const size_t SP = (size_t)SEQ * DIM;
    float4 a0 = *(const float4*)(x + base);
    float4 a1 = *(const float4*)(x + base + 4);
    bf16x8 p0 = *(const bf16x8*)(part + base);
    bf16x8 p1 = *(const bf16x8*)(part + SP + base);
    bf16x8 p2 = *(const bf16x8*)(part + 2 * SP + base);
    bf16x8 p3 = *(const bf16x8*)(part + 3 * SP + base);
    float r8[8];
    float ss = 0.0f;
#pragma unroll
    for (int e = 0; e < 8; ++e) {
        const float xa = e < 4 ? (&a0.x)[e] : (&a1.x)[e - 4];
        const float v = xa + ((bu2f((unsigned short)p0[e]) + bu2f((unsigned short)p1[e]))
                            + (bu2f((unsigned short)p2[e]) + bu2f((unsigned short)p3[e])));
        r8[e] = v;
        ss += v * v;
    }
    *(float4*)(hout + base)     = make_float4(r8[0], r8[1], r8[2], r8[3]);
    *(float4*)(hout + base + 4) = make_float4(r8[4], r8[5], r8[6], r8[7]);
    for (int o = 32; o > 0; o >>= 1) ss += __shfl_down(ss, o);
    __shared__ float red[4];
    if ((tid & 63) == 0) red[tid >> 6] = ss;
    __syncthreads();
    float tot = red[0] + red[1] + red[2] + red[3];
    float r = rsqrtf(tot * (1.0f / DIM) + 1e-6f);
    float4 w0 = *(const float4*)(w + tid * 8);
    float4 w1 = *(const float4*)(w + tid * 8 + 4);
    bf16x8 o8;
#pragma unroll
    for (int e = 0; e < 8; ++e) {
        const float ww = e < 4 ? (&w0.x)[e] : (&w1.x)[e - 4];
        o8[e] = (short)f2bu(r8[e] * r * ww);
    }
    *(bf16x8*)((unsigned short*)y + base) = o8;
}

// ---------------- split-K(bf16) reduce + residual (fp32 out) ----------------
__global__ __launch_bounds__(256) void reduce4_k(
    const bf16* __restrict__ part, const float* __restrict__ h, float* __restrict__ out)
{
    const size_t i = ((size_t)blockIdx.x * 256 + threadIdx.x) * 8;
    const size_t SP = (size_t)SEQ * DIM;
    float4 a0 = *(const float4*)(h + i);
    float4 a1 = *(const float4*)(h + i + 4);
    bf16x8 p0 = *(const bf16x8*)(part + i);
    bf16x8 p1 = *(const bf16x8*)(part + SP + i);
    bf16x8 p2 = *(const bf16x8*)(part + 2 * SP + i);
    bf16x8 p3 = *(const bf16x8*)(part + 3 * SP + i);
    float r8[8];
#pragma unroll
    for (int e = 0; e < 8; ++e) {
        const float xa = e < 4 ? (&a0.x)[e] : (&a1.x)[e - 4];
        r8[e] = xa + ((bu2f((unsigned short)p0[e]) + bu2f((unsigned short)p1[e]))
                    + (bu2f((unsigned short)p2[e]) + bu2f((unsigned short)p3[e])));
    }
    *(float4*)(out + i)     = make_float4(r8[0], r8[1], r8[2], r8[3]);
    *(float4*)(out + i + 4) = make_float4(r8[4], r8[5], r8[6], r8[7]);
}

// ---------------- fp32 [R][C] -> bf16 [C][R], 64x64 tile, vectorized ----------------
__device__ __forceinline__ void convT64_body(
    const float* __restrict__ in, bf16* __restrict__ out, int R, int C,
    int bx, int by)
{
    __shared__ unsigned short t[64][72];
    const int tid = threadIdx.x;
    const int x0 = bx * 64;
    const int y0 = by * 64;
    const int tx = tid & 15, ty = tid >> 4;
#pragma unroll
    for (int i = 0; i < 4; ++i) {
        const int row = ty + i * 16;
        float4 v = *(const float4*)(in + (size_t)(y0 + row) * C + x0 + tx * 4);
        t[tx * 4 + 0][row] = f2bu(v.x);
        t[tx * 4 + 1][row] = f2bu(v.y);
        t[tx * 4 + 2][row] = f2bu(v.z);
        t[tx * 4 + 3][row] = f2bu(v.w);
    }
    __syncthreads();
    const int rx = tid & 7, cy = tid >> 3;
#pragma unroll
    for (int i = 0; i < 2; ++i) {
        const int c = cy + i * 32;
        bf16x8 v = *(const bf16x8*)&t[c][rx * 8];
        *(bf16x8*)(out + (size_t)(x0 + c) * R + y0 + rx * 8) = v;
    }
}

__global__ __launch_bounds__(256) void convT64_k(
    const float* __restrict__ in, bf16* __restrict__ out, int R, int C)
{
    convT64_body(in, out, R, C, blockIdx.x, blockIdx.y);
}

__global__ __launch_bounds__(256) void convT64q_k(
    const float* __restrict__ wq, const float* __restrict__ wk,
    const float* __restrict__ wv, bf16* __restrict__ out)
{
    const int z = blockIdx.z;
    const float* in = z == 0 ? wq : (z == 1 ? wk : wv);
    convT64_body(in, out + (size_t)z * DIM * DIM, DIM, DIM, blockIdx.x, blockIdx.y);
}

__global__ __launch_bounds__(256) void convT64f_k(
    const float* __restrict__ w1, const float* __restrict__ w3,
    bf16* __restrict__ o1, bf16* __restrict__ o3)
{
    const int z = blockIdx.z;
    convT64_body(z ? w3 : w1, z ? o3 : o1, DIM, HID, blockIdx.x, blockIdx.y);
}

// ---------------- bf16 transpose with src stride (vt[d][s] = in[s][d]) ----------------
__global__ __launch_bounds__(256) void transpose_bf16_k(
    const bf16* __restrict__ in, int istride, bf16* __restrict__ out)
{
    __shared__ unsigned short t[32][33];
    const int tx = threadIdx.x & 31, ty = threadIdx.x >> 5;
    const int x = blockIdx.x * 32 + tx;
    const int y0 = blockIdx.y * 32;
    const unsigned short* inu = (const unsigned short*)in;
    unsigned short* outu = (unsigned short*)out;
#pragma unroll
    for (int i = 0; i < 4; ++i)
        t[ty + i * 8][tx] = inu[(size_t)(y0 + ty + i * 8) * istride + x];
    __syncthreads();
    const int x2 = blockIdx.y * 32 + tx;
    const int y2 = blockIdx.x * 32;
#pragma unroll
    for (int i = 0; i < 4; ++i)
        outu[(size_t)(y2 + ty + i * 8) * SEQ + x2] = t[tx][ty + i * 8];
}

// ---------------- RoPE in-place, vectorized: 8 elems (4 pairs) per thread ----------------
__global__ __launch_bounds__(256) void rope_qk_k(
    bf16* __restrict__ q, bf16* __restrict__ k,
    const float* __restrict__ cosb, const float* __restrict__ sinb)
{
    const int gid = blockIdx.x * 256 + threadIdx.x;   // < SEQ * 256
    const int s = gid >> 8;
    const int p8 = gid & 255;
    const size_t off = (size_t)s * SQKV + p8 * 8;
    const int j0 = ((p8 * 8) & 127) >> 1;             // 0,4,...,60
    float4 c4 = *(const float4*)(cosb + s * 64 + j0);
    float4 s4 = *(const float4*)(sinb + s * 64 + j0);
    bf16x8 qv = *(const bf16x8*)((const unsigned short*)q + off);
    bf16x8 kv = *(const bf16x8*)((const unsigned short*)k + off);
    bf16x8 qo, ko;
#pragma unroll
    for (int e = 0; e < 4; ++e) {
        const float c = (&c4.x)[e], sn = (&s4.x)[e];
        float xr = bu2f((unsigned short)qv[2 * e]), xi = bu2f((unsigned short)qv[2 * e + 1]);
        qo[2 * e]     = (short)f2bu(xr * c - xi * sn);
        qo[2 * e + 1] = (short)f2bu(xr * sn + xi * c);
        xr = bu2f((unsigned short)kv[2 * e]); xi = bu2f((unsigned short)kv[2 * e + 1]);
        ko[2 * e]     = (short)f2bu(xr * c - xi * sn);
        ko[2 * e + 1] = (short)f2bu(xr * sn + xi * c);
    }
    *(bf16x8*)((unsigned short*)q + off) = qo;
    *(bf16x8*)((unsigned short*)k + off) = ko;
}

// ---------------- 256x256 GEMM, 8-phase skeleton, 32x32x16 MFMA, split-K ----------------
// EP 0: store bf16    EP 3: bf16 partial store    EP 4: fused w1|w3 silu-mul
// Fragments: A/B lane holds [row=l&31][k=(l>>5)*8+e]; C/D col=l&31,
// row=(reg&3)+8*(reg>>2)+4*(l>>5) (m74/m101). Per phase: 4 A ds_reads + 8 MFMA.
// EP4: lanes l and l^16 hold w1/w3 products of the SAME j -> shfl_xor(16) pairing.
// R16 FIX: the full column byte offset (kh*16 + ks*32) goes INSIDE the swizzle XOR
// (R15 added kh*16 outside -> carries into bits>=5 -> row-crossing/OOB LDS reads -> NaN).
template <int EP>
__global__ __launch_bounds__(512, 1) void gemm256_k(
    const bf16* __restrict__ A, const bf16* __restrict__ Bt, const bf16* __restrict__ Bt2,
    bf16* __restrict__ Cb,
    int M, int N, int K, int gx, int ntile, int Ks)
{
    extern __shared__ char smem[];
    const int t512 = threadIdx.x;
    const int w = t512 >> 6, lane = t512 & 63;
    const int l31 = lane & 31, kh = lane >> 5;
    const int wm = w >> 2, wn = w & 3;           // 2 x 4 wave grid
    const int bofs = (wn & 1) * 64;              // B row offset inside its half
    const int swz = (l31 & 7) << 4;              // ds_read swizzle
    const int cb0 = kh * 16;                     // lane's K-half byte offset

    // XCD-bijective block swizzle (m204)
    const int nwg = gridDim.x;
    const int q8 = nwg >> 3, r8 = nwg & 7;
    const int xcd = blockIdx.x & 7, seqq = blockIdx.x >> 3;
    const int wgid = (xcd < r8 ? xcd * (q8 + 1) : r8 * (q8 + 1) + (xcd - r8) * q8) + seqq;
    const int split = wgid / ntile;
    const int tile = wgid % ntile;
    // GROUP_M=4 supertiling
    const int grp = tile / (4 * gx), rem = tile % (4 * gx);
    const int m0 = (grp * 4 + (rem & 3)) * 256, n0 = (rem >> 2) * 256;
    const int kb0 = split * Ks;
    const int niter = Ks >> 7;

    // staging source pointers (pre-swizzled)
    const bf16* aS[2][2]; const bf16* bS[2][2];
    int sOff[2];
#pragma unroll
    for (int c = 0; c < 2; ++c) {
        const int s = (c * 512 + t512) * 16;
        const int pp = s ^ (((s >> 7) & 7) << 4);
        const int row = pp >> 7, colE = (pp & 127) >> 1;
        sOff[c] = s;
#pragma unroll
        for (int hs = 0; hs < 2; ++hs) {
            aS[hs][c] = A + (size_t)(m0 + hs * 128 + row) * K + kb0 + colE;
            const int rg = n0 + hs * 128 + row;
            if (EP == 4) {
                const int g = rg >> 4;
                const bf16* src = (g & 1) ? Bt2 : Bt;
                const int j = ((g >> 1) << 4) + (rg & 15);
                bS[hs][c] = src + (size_t)j * K + kb0 + colE;
            } else {
                bS[hs][c] = Bt + (size_t)rg * K + kb0 + colE;
            }
        }
    }
    auto stA = [&](int buf, int kt, int hs) {
        char* base = smem + (buf * 2 + hs) * 16384;
        gl16(aS[hs][0] + (kt << 6), base + sOff[0]);
        gl16(aS[hs][1] + (kt << 6), base + sOff[1]);
    };
    auto stB = [&](int buf, int kt, int hs) {
        char* base = smem + 65536 + (buf * 2 + hs) * 16384;
        gl16(bS[hs][0] + (kt << 6), base + sOff[0]);
        gl16(bS[hs][1] + (kt << 6), base + sOff[1]);
    };

    const char* A0m = smem + (0 * 2 + wm) * 16384;
    const char* A1m = smem + (1 * 2 + wm) * 16384;
    const char* B0m = smem + 65536 + (0 * 2 + (wn >> 1)) * 16384;
    const char* B1m = smem + 65536 + (1 * 2 + (wn >> 1)) * 16384;

    f32x16 acc[4][2] = {};
    bf16x8 bfr[2][4];                    // [nf][ks]
    bf16x8 af0, af1, af2, af3;           // A frags for this phase (ks 0..3)

#define SBAR __builtin_amdgcn_s_barrier()
#define LGKM0 do { asm volatile("s_waitcnt lgkmcnt(0)" ::: "memory"); \
                   __builtin_amdgcn_sched_barrier(0); } while (0)
#define WVM(n) do { asm volatile("s_waitcnt vmcnt(" #n ")" ::: "memory"); \
                    __builtin_amdgcn_sched_barrier(0); } while (0)
#define LDA32(base, mf) do { \
    const char* rb_ = (base) + (((mf) * 32 + l31) * 128); \
    af0 = *(const bf16x8*)(rb_ + ((cb0 + 0)  ^ swz)); \
    af1 = *(const bf16x8*)(rb_ + ((cb0 + 32) ^ swz)); \
    af2 = *(const bf16x8*)(rb_ + ((cb0 + 64) ^ swz)); \
    af3 = *(const bf16x8*)(rb_ + ((cb0 + 96) ^ swz)); \
    } while (0)
#define LDB32(base) do { \
    _Pragma("unroll") \
    for (int nf = 0; nf < 2; ++nf) { \
        const char* rb_ = (base) + ((bofs + nf * 32 + l31) * 128); \
        bfr[nf][0] = *(const bf16x8*)(rb_ + ((cb0 + 0)  ^ swz)); \
        bfr[nf][1] = *(const bf16x8*)(rb_ + ((cb0 + 32) ^ swz)); \
        bfr[nf][2] = *(const bf16x8*)(rb_ + ((cb0 + 64) ^ swz)); \
        bfr[nf][3] = *(const bf16x8*)(rb_ + ((cb0 + 96) ^ swz)); \
    } } while (0)
#define MFMA_PH(mf) do { \
    __builtin_amdgcn_s_setprio(1); \
    acc[mf][0] = MFMA32(af0, bfr[0][0], acc[mf][0]); \
    acc[mf][1] = MFMA32(af0, bfr[1][0], acc[mf][1]); \
    acc[mf][0] = MFMA32(af1, bfr[0][1], acc[mf][0]); \
    acc[mf][1] = MFMA32(af1, bfr[1][1], acc[mf][1]); \
    acc[mf][0] = MFMA32(af2, bfr[0][2], acc[mf][0]); \
    acc[mf][1] = MFMA32(af2, bfr[1][2], acc[mf][1]); \
    acc[mf][0] = MFMA32(af3, bfr[0][3], acc[mf][0]); \
    acc[mf][1] = MFMA32(af3, bfr[1][3], acc[mf][1]); \
    __builtin_amdgcn_s_setprio(0); } while (0)

    // prologue
    stB(0, 0, 0); stB(0, 0, 1); stA(0, 0, 0); stA(0, 0, 1);
    stB(1, 1, 0); stB(1, 1, 1);
    WVM(4);
    SBAR;

    for (int t = 0; t < niter; ++t) {
        const bool pf = (t + 1 < niter);
        const int k1 = 2 * t + 1, k2 = 2 * t + 2, k3 = 2 * t + 3;

        // ---- ph1 ----
        LDB32(B0m);
        LDA32(A0m, 0);
        stA(1, k1, 0);
        SBAR; LGKM0; MFMA_PH(0); SBAR;
        // ---- ph2 ----
        LDA32(A0m, 1);
        stA(1, k1, 1);
        SBAR; LGKM0; MFMA_PH(1); SBAR;
        // ---- ph3 ----
        LDA32(A0m, 2);
        if (pf) stB(0, k2, 0);
        SBAR; LGKM0; MFMA_PH(2); SBAR;
        // ---- ph4 ----
        if (pf) { WVM(2); } else { WVM(0); }
        LDA32(A0m, 3);
        if (pf) stB(0, k2, 1);
        SBAR; LGKM0; MFMA_PH(3); SBAR;
        // ---- ph5 ----
        LDB32(B1m);
        LDA32(A1m, 0);
        if (pf) stA(0, k2, 0);
        SBAR; LGKM0; MFMA_PH(0); SBAR;
        // ---- ph6 ----
        LDA32(A1m, 1);
        if (pf) stA(0, k2, 1);
        SBAR; LGKM0; MFMA_PH(1); SBAR;
        // ---- ph7 ----
        LDA32(A1m, 2);
        if (pf) stB(1, k3, 0);
        SBAR; LGKM0; MFMA_PH(2); SBAR;
        // ---- ph8 ----
        if (pf) WVM(2);
        LDA32(A1m, 3);
        if (pf) stB(1, k3, 1);
        SBAR; LGKM0; MFMA_PH(3); SBAR;
    }
#undef SBAR
#undef LGKM0
#undef WVM
#undef LDA32
#undef LDB32
#undef MFMA_PH

    // ---- epilogue ----
    if (EP == 4) {
        const int NH = N >> 1;                  // = HID
#pragma unroll
        for (int mf = 0; mf < 4; ++mf)
#pragma unroll
            for (int nf = 0; nf < 2; ++nf) {
                const int jb = (((n0 + wn * 64 + nf * 32) >> 5) << 4) + (lane & 15);
#pragma unroll
                for (int reg = 0; reg < 16; ++reg) {
                    const float v = acc[mf][nf][reg];
                    const float vp = __shfl_xor(v, 16);
                    if ((lane & 31) < 16) {
                        const int row = m0 + wm * 128 + mf * 32
                                      + (reg & 3) + 8 * (reg >> 2) + 4 * kh;
                        const float s = v / (1.0f + __expf(-v));
                        Cb[(size_t)row * NH + jb] = __float2bfloat16(s * vp);
                    }
                }
            }
    } else {
        bf16* cb = (EP == 3) ? Cb + (size_t)split * M * N : Cb;
#pragma unroll
        for (int mf = 0; mf < 4; ++mf)
#pragma unroll
            for (int nf = 0; nf < 2; ++nf) {
                const int col = n0 + wn * 64 + nf * 32 + l31;
#pragma unroll
                for (int reg = 0; reg < 16; ++reg) {
                    const int row = m0 + wm * 128 + mf * 32
                                  + (reg & 3) + 8 * (reg >> 2) + 4 * kh;
                    cb[(size_t)row * N + col] = __float2bfloat16(acc[mf][nf][reg]);
                }
            }
    }
}

// ---------------- causal flash attention: paired q-tiles, 8 waves, shared KV ----------------
__global__ __launch_bounds__(512) void attn_fwd_k(
    const bf16* __restrict__ qkv, const bf16* __restrict__ vT, bf16* __restrict__ ctx)
{
    const int tid = threadIdx.x;
    const int w8 = tid >> 6, lane = tid & 63;
    const int lr = lane & 15, lg = lane >> 4;
    const int w = w8 & 3, tsel = w8 >> 2;
    const int h = blockIdx.y;
    const int bx = blockIdx.x;                    // 0..15
    const int qidx = tsel ? (31 - bx) : bx;
    const int q0b = qidx * 64;
    const int myNt = qidx + 1;
    const int nt = 32 - bx;

    __shared__ __align__(16) unsigned short Kt[2][64 * 128];
    __shared__ __align__(16) unsigned short Vt[128 * 64];
    __shared__ __align__(16) unsigned short Pp[8][16 * 64];

    const char* kbase = (const char*)(qkv + DIM + h * HEAD_DIM);
    const char* vbase = (const char*)(vT + (size_t)h * HEAD_DIM * SEQ);

    const int krow_c = tid >> 4;
    const int kcolB  = (tid & 15) * 16;
    const int vrow_c = tid >> 3;
    const int vcolB  = (tid & 7) * 16;

    auto stageK = [&](int buf, int kb) {
#pragma unroll
        for (int c = 0; c < 2; ++c) {
            const int r = c * 32 + krow_c;
            gl16(kbase + (size_t)(kb + r) * (SQKV * 2) + (kcolB ^ ((r & 7) << 4)),
                 &Kt[buf][c * 4096 + tid * 8]);
        }
    };
    auto stageV = [&](int kb) {
#pragma unroll
        for (int c = 0; c < 2; ++c) {
            const int r = c * 64 + vrow_c;
            gl16(vbase + (size_t)r * (SEQ * 2) + kb * 2 + (vcolB ^ ((r & 7) << 4)),
                 &Vt[c * 4096 + tid * 8]);
        }
    };

    bf16x8 qf[4];
    const bf16* qrow = qkv + (size_t)(q0b + w * 16 + lr) * SQKV + h * HEAD_DIM;
#pragma unroll
    for (int dt = 0; dt < 4; ++dt)
        qf[dt] = *(const bf16x8*)(qrow + dt * 32 + lg * 8);

    f32x4 o[8] = {};
    float m[4], l[4];
#pragma unroll
    for (int j = 0; j < 4; ++j) { m[j] = -3e38f; l[j] = 0.0f; }
    const float scale = 0.08838834764831845f;

    stageK(0, 0);
    asm volatile("s_waitcnt vmcnt(0)" ::: "memory");
    __builtin_amdgcn_sched_barrier(0);
    __builtin_amdgcn_s_barrier();

    int cur = 0;
    for (int t = 0; t < nt; ++t) {
        const int kb = t * 64;
        const bool pf = (t + 1 < nt);
        stageV(kb);
        if (pf) stageK(cur ^ 1, kb + 64);
        const bool act = (t < myNt);

        if (act) {
            f32x4 s[4] = {};
            __builtin_amdgcn_s_setprio(1);
#pragma unroll
            for (int ss = 0; ss < 4; ++ss) {
                const int r = ss * 16 + lr;
                const int sw = (r & 7) << 3;
#pragma unroll
                for (int dt = 0; dt < 4; ++dt) {
                    bf16x8 kf = *(const bf16x8*)&Kt[cur][r * 128 + ((dt * 32 + lg * 8) ^ sw)];
                    s[ss] = MFMA16(qf[dt], kf, s[ss]);
                }
            }
            __builtin_amdgcn_s_setprio(0);

            float al[4];
#pragma unroll
            for (int j = 0; j < 4; ++j) {
                const int qi = q0b + w * 16 + lg * 4 + j;
                const int prow = lg * 4 + j;
                const int psw = (prow & 7) << 3;
                float a[4];
#pragma unroll
                for (int ss = 0; ss < 4; ++ss)
                    a[ss] = s[ss][j] * scale + ((kb + ss * 16 + lr) > qi ? -1e9f : 0.0f);
                float mx = fmaxf(fmaxf(a[0], a[1]), fmaxf(a[2], a[3]));
                mx = fmaxf(mx, __shfl_xor(mx, 1));
                mx = fmaxf(mx, __shfl_xor(mx, 2));
                mx = fmaxf(mx, __shfl_xor(mx, 4));
                mx = fmaxf(mx, __shfl_xor(mx, 8));
                const float mn = fmaxf(m[j], mx);
                const float asc = __expf(m[j] - mn);
                float e0 = __expf(a[0] - mn), e1 = __expf(a[1] - mn);
                float e2 = __expf(a[2] - mn), e3 = __expf(a[3] - mn);
                float rs = (e0 + e1) + (e2 + e3);
                rs += __shfl_xor(rs, 1); rs += __shfl_xor(rs, 2);
                rs += __shfl_xor(rs, 4); rs += __shfl_xor(rs, 8);
                l[j] = l[j] * asc + rs;
                m[j] = mn;
                al[j] = asc;
                Pp[w8][prow * 64 + ((lr)      ^ psw)] = f2bu(e0);
                Pp[w8][prow * 64 + ((16 + lr) ^ psw)] = f2bu(e1);
                Pp[w8][prow * 64 + ((32 + lr) ^ psw)] = f2bu(e2);
                Pp[w8][prow * 64 + ((48 + lr) ^ psw)] = f2bu(e3);
            }
#pragma unroll
            for (int d2 = 0; d2 < 8; ++d2)
#pragma unroll
                for (int j = 0; j < 4; ++j) o[d2][j] *= al[j];
        }

        if (pf) { asm volatile("s_waitcnt vmcnt(2)" ::: "memory"); }
        else    { asm volatile("s_waitcnt vmcnt(0)" ::: "memory"); }
        __builtin_amdgcn_sched_barrier(0);
        __builtin_amdgcn_s_barrier();

        if (act) {
            asm volatile("s_waitcnt lgkmcnt(0)" ::: "memory");
            __builtin_amdgcn_sched_barrier(0);
            const int asw = (lr & 7) << 3;
            bf16x8 pa0 = *(const bf16x8*)&Pp[w8][lr * 64 + ((lg * 8)      ^ asw)];
            bf16x8 pa1 = *(const bf16x8*)&Pp[w8][lr * 64 + ((32 + lg * 8) ^ asw)];

            __builtin_amdgcn_s_setprio(1);
#pragma unroll
            for (int d2 = 0; d2 < 8; ++d2) {
                const int rv = d2 * 16 + lr;
                const int vsw = (rv & 7) << 3;
                bf16x8 vf0 = *(const bf16x8*)&Vt[rv * 64 + ((lg * 8)      ^ vsw)];
                bf16x8 vf1 = *(const bf16x8*)&Vt[rv * 64 + ((32 + lg * 8) ^ vsw)];
                o[d2] = MFMA16(pa0, vf0, o[d2]);
                o[d2] = MFMA16(pa1, vf1, o[d2]);
            }
            __builtin_amdgcn_s_setprio(0);
        }

        __builtin_amdgcn_s_barrier();
        cur ^= 1;
    }

#pragma unroll
    for (int j = 0; j < 4; ++j) {
        const float inv = 1.0f / l[j];
        bf16* dst = ctx + (size_t)(q0b + w * 16 + lg * 4 + j) * DIM + h * HEAD_DIM + lr;
#pragma unroll
        for (int d2 = 0; d2 < 8; ++d2)
            dst[d2 * 16] = __float2bfloat16(o[d2][j] * inv);
    }
}

// ---------------- host ----------------
extern "C" void kernel_launch(void* const* d_in, const int* in_sizes, int n_in,
                              void* d_out, int out_size, void* d_ws, size_t ws_size,
                              hipStream_t stream)
{
    const float* x   = (const float*)d_in[0];
    const float* fc  = (const float*)d_in[1];
    const float* fs  = (const float*)d_in[2];
    // d_in[3] = mask (unused; causal computed analytically)
    const float* wq  = (const float*)d_in[4];
    const float* wk  = (const float*)d_in[5];
    const float* wv  = (const float*)d_in[6];
    const float* wo  = (const float*)d_in[7];
    const float* w1  = (const float*)d_in[8];
    const float* w2  = (const float*)d_in[9];
    const float* w3  = (const float*)d_in[10];
    const float* anw = (const float*)d_in[11];
    const float* fnw = (const float*)d_in[12];
    float* out = (float*)d_out;

    char* p = (char*)d_ws;
    auto alloc = [&](size_t n) { char* r = p; p += (n + 255) & ~(size_t)255; return r; };
    bf16* wT  = (bf16*)alloc((size_t)HID * DIM * 2);
    bf16* hn  = (bf16*)alloc((size_t)SEQ * DIM * 2);     // dead after QKV GEMM
    bf16* qkv = (bf16*)alloc((size_t)SEQ * SQKV * 2);    // dead after attn
    bf16* vt  = (bf16*)alloc((size_t)SEQ * DIM * 2);
    bf16* ctx = (bf16*)alloc((size_t)SEQ * DIM * 2);
    bf16* fn  = (bf16*)alloc((size_t)SEQ * DIM * 2);
    float* h  = (float*)alloc((size_t)SEQ * DIM * 4);
    bf16* g   = (bf16*)alloc((size_t)SEQ * HID * 2);
    bf16* sk  = (bf16*)alloc((size_t)4 * SEQ * DIM * 2);
    bf16* w3T = hn;   // aliases hn+qkv (dead by then)

    const int LDS256 = 131072;
    (void)hipFuncSetAttribute((const void*)gemm256_k<0>,
        hipFuncAttributeMaxDynamicSharedMemorySize, LDS256);
    (void)hipFuncSetAttribute((const void*)gemm256_k<3>,
        hipFuncAttributeMaxDynamicSharedMemorySize, LDS256);
    (void)hipFuncSetAttribute((const void*)gemm256_k<4>,
        hipFuncAttributeMaxDynamicSharedMemorySize, LDS256);

    rmsnorm_bf16_k<<<SEQ, 256, 0, stream>>>(x, anw, hn);

    convT64q_k<<<dim3(DIM / 64, DIM / 64, 3), 256, 0, stream>>>(wq, wk, wv, wT);
    gemm256_k<0><<<(SEQ / 256) * (SQKV / 256), 512, LDS256, stream>>>(
        hn, wT, nullptr, qkv, SEQ, SQKV, DIM, SQKV / 256, (SEQ / 256) * (SQKV / 256), DIM);

    rope_qk_k<<<(SEQ * 256) / 256, 256, 0, stream>>>(qkv, qkv + DIM, fc, fs);
    transpose_bf16_k<<<dim3(DIM / 32, SEQ / 32), 256, 0, stream>>>(qkv + 2 * DIM, SQKV, vt);

    attn_fwd_k<<<dim3(16, N_HEADS), 512, 0, stream>>>(qkv, vt, ctx);

    convT64_k<<<dim3(DIM / 64, DIM / 64), 256, 0, stream>>>(wo, wT, DIM, DIM);
    gemm256_k<3><<<(SEQ / 256) * (DIM / 256) * 4, 512, LDS256, stream>>>(
        ctx, wT, nullptr, sk, SEQ, DIM, DIM, DIM / 256, (SEQ / 256) * (DIM / 256), 512);
    rmsnorm4_k<<<SEQ, 256, 0, stream>>>(sk, x, fnw, h, fn);

    convT64f_k<<<dim3(HID / 64, DIM / 64, 2), 256, 0, stream>>>(w1, w3, wT, w3T);
    gemm256_k<4><<<(SEQ / 256) * ((2 * HID) / 256), 512, LDS256, stream>>>(
        fn, wT, w3T, g, SEQ, 2 * HID, DIM, (2 * HID) / 256,
        (SEQ / 256) * ((2 * HID) / 256), DIM);

    convT64_k<<<dim3(DIM / 64, HID / 64), 256, 0, stream>>>(w2, wT, HID, DIM);
    gemm256_k<3><<<(SEQ / 256) * (DIM / 256) * 4, 512, LDS256, stream>>>(
        g, wT, nullptr, sk, SEQ, DIM, HID, DIM / 256, (SEQ / 256) * (DIM / 256), 2048);
    reduce4_k<<<(SEQ * DIM / 8) / 256, 256, 0, stream>>>(sk, h, out);
}

// Round 17
// 448.961 us; speedup vs baseline: 1.0899x; 1.0899x over previous
//
#include <hip/hip_runtime.h>
#include <hip/hip_bf16.h>

#define DIM 2048
#define HEAD_DIM 128
#define N_HEADS 16
#define SEQ 2048
#define HID 8192
#define SQKV 6144   // row stride of fused qkv activation

typedef short bf16x8 __attribute__((ext_vector_type(8)));
typedef float f32x4 __attribute__((ext_vector_type(4)));
using bf16 = __hip_bfloat16;

#define MFMA16(a, b, c) __builtin_amdgcn_mfma_f32_16x16x32_bf16(a, b, c, 0, 0, 0)

__device__ __forceinline__ unsigned short f2bu(float f) {
    union { bf16 b; unsigned short u; } cv;
    cv.b = __float2bfloat16(f);
    return cv.u;
}
__device__ __forceinline__ float bu2f(unsigned short u) {
    union { unsigned short u; bf16 b; } cv;
    cv.u = u;
    return __bfloat162float(cv.b);
}

// async global -> LDS, 16B per lane (dest must be lane-linear per wave)
__device__ __forceinline__ void gl16(const void* g, void* l) {
    __builtin_amdgcn_global_load_lds(
        (const __attribute__((address_space(1))) unsigned int*)g,
        (__attribute__((address_space(3))) unsigned int*)l, 16, 0, 0);
}

// ---------------- rmsnorm (fp32 in -> bf16 out) ----------------
__global__ __launch_bounds__(256) void rmsnorm_bf16_k(
    const float* __restrict__ x, const float* __restrict__ w, bf16* __restrict__ y)
{
    const int row = blockIdx.x;
    const int tid = threadIdx.x;
    const float* xr = x + (size_t)row * DIM;
    float4 v0 = ((const float4*)xr)[tid];
    float4 v1 = ((const float4*)xr)[tid + 256];
    float ss = v0.x*v0.x + v0.y*v0.y + v0.z*v0.z + v0.w*v0.w
             + v1.x*v1.x + v1.y*v1.y + v1.z*v1.z + v1.w*v1.w;
    for (int o = 32; o > 0; o >>= 1) ss += __shfl_down(ss, o);
    __shared__ float red[4];
    if ((tid & 63) == 0) red[tid >> 6] = ss;
    __syncthreads();
    float tot = red[0] + red[1] + red[2] + red[3];
    float r = rsqrtf(tot * (1.0f / DIM) + 1e-6f);
    float4 w0 = ((const float4*)w)[tid];
    float4 w1 = ((const float4*)w)[tid + 256];
    ushort4 o0, o1;
    o0.x = f2bu(v0.x * r * w0.x); o0.y = f2bu(v0.y * r * w0.y);
    o0.z = f2bu(v0.z * r * w0.z); o0.w = f2bu(v0.w * r * w0.w);
    o1.x = f2bu(v1.x * r * w1.x); o1.y = f2bu(v1.y * r * w1.y);
    o1.z = f2bu(v1.z * r * w1.z); o1.w = f2bu(v1.w * r * w1.w);
    ushort4* yr = (ushort4*)(y + (size_t)row * DIM);
    yr[tid] = o0;
    yr[tid + 256] = o1;
}

// ---------------- split-K(bf16) reduce + residual + rmsnorm (fp32 h out, bf16 fn out) ----------------
__global__ __launch_bounds__(256) void rmsnorm4_k(
    const bf16* __restrict__ part, const float* __restrict__ x,
    const float* __restrict__ w, float* __restrict__ hout, bf16* __restrict__ y)
{
    const int row = blockIdx.x;
    const int tid = threadIdx.x;
    const size_t base = (size_t)row * DIM + tid * 8;
    const size_t SP = (size_t)SEQ * DIM;
    float4 a0 = *(const float4*)(x + base);
    float4 a1 = *(const float4*)(x + base + 4);
    bf16x8 p0 = *(const bf16x8*)(part + base);
    bf16x8 p1 = *(const bf16x8*)(part + SP + base);
    bf16x8 p2 = *(const bf16x8*)(part + 2 * SP + base);
    bf16x8 p3 = *(const bf16x8*)(part + 3 * SP + base);
    float r8[8];
    float ss = 0.0f;
#pragma unroll
    for (int e = 0; e < 8; ++e) {
        const float xa = e < 4 ? (&a0.x)[e] : (&a1.x)[e - 4];
        const float v = xa + ((bu2f((unsigned short)p0[e]) + bu2f((unsigned short)p1[e]))
                            + (bu2f((unsigned short)p2[e]) + bu2f((unsigned short)p3[e])));
        r8[e] = v;
        ss += v * v;
    }
    *(float4*)(hout + base)     = make_float4(r8[0], r8[1], r8[2], r8[3]);
    *(float4*)(hout + base + 4) = make_float4(r8[4], r8[5], r8[6], r8[7]);
    for (int o = 32; o > 0; o >>= 1) ss += __shfl_down(ss, o);
    __shared__ float red[4];
    if ((tid & 63) == 0) red[tid >> 6] = ss;
    __syncthreads();
    float tot = red[0] + red[1] + red[2] + red[3];
    float r = rsqrtf(tot * (1.0f / DIM) + 1e-6f);
    float4 w0 = *(const float4*)(w + tid * 8);
    float4 w1 = *(const float4*)(w + tid * 8 + 4);
    bf16x8 o8;
#pragma unroll
    for (int e = 0; e < 8; ++e) {
        const float ww = e < 4 ? (&w0.x)[e] : (&w1.x)[e - 4];
        o8[e] = (short)f2bu(r8[e] * r * ww);
    }
    *(bf16x8*)((unsigned short*)y + base) = o8;
}

// ---------------- split-K(bf16) reduce + residual (fp32 out) ----------------
__global__ __launch_bounds__(256) void reduce4_k(
    const bf16* __restrict__ part, const float* __restrict__ h, float* __restrict__ out)
{
    const size_t i = ((size_t)blockIdx.x * 256 + threadIdx.x) * 8;
    const size_t SP = (size_t)SEQ * DIM;
    float4 a0 = *(const float4*)(h + i);
    float4 a1 = *(const float4*)(h + i + 4);
    bf16x8 p0 = *(const bf16x8*)(part + i);
    bf16x8 p1 = *(const bf16x8*)(part + SP + i);
    bf16x8 p2 = *(const bf16x8*)(part + 2 * SP + i);
    bf16x8 p3 = *(const bf16x8*)(part + 3 * SP + i);
    float r8[8];
#pragma unroll
    for (int e = 0; e < 8; ++e) {
        const float xa = e < 4 ? (&a0.x)[e] : (&a1.x)[e - 4];
        r8[e] = xa + ((bu2f((unsigned short)p0[e]) + bu2f((unsigned short)p1[e]))
                    + (bu2f((unsigned short)p2[e]) + bu2f((unsigned short)p3[e])));
    }
    *(float4*)(out + i)     = make_float4(r8[0], r8[1], r8[2], r8[3]);
    *(float4*)(out + i + 4) = make_float4(r8[4], r8[5], r8[6], r8[7]);
}

// ---------------- fp32 [R][C] -> bf16 [C][R], 64x64 tile, vectorized ----------------
__device__ __forceinline__ void convT64_body(
    const float* __restrict__ in, bf16* __restrict__ out, int R, int C,
    int bx, int by)
{
    __shared__ unsigned short t[64][72];
    const int tid = threadIdx.x;
    const int x0 = bx * 64;
    const int y0 = by * 64;
    const int tx = tid & 15, ty = tid >> 4;
#pragma unroll
    for (int i = 0; i < 4; ++i) {
        const int row = ty + i * 16;
        float4 v = *(const float4*)(in + (size_t)(y0 + row) * C + x0 + tx * 4);
        t[tx * 4 + 0][row] = f2bu(v.x);
        t[tx * 4 + 1][row] = f2bu(v.y);
        t[tx * 4 + 2][row] = f2bu(v.z);
        t[tx * 4 + 3][row] = f2bu(v.w);
    }
    __syncthreads();
    const int rx = tid & 7, cy = tid >> 3;
#pragma unroll
    for (int i = 0; i < 2; ++i) {
        const int c = cy + i * 32;
        bf16x8 v = *(const bf16x8*)&t[c][rx * 8];
        *(bf16x8*)(out + (size_t)(x0 + c) * R + y0 + rx * 8) = v;
    }
}

__global__ __launch_bounds__(256) void convT64_k(
    const float* __restrict__ in, bf16* __restrict__ out, int R, int C)
{
    convT64_body(in, out, R, C, blockIdx.x, blockIdx.y);
}

__global__ __launch_bounds__(256) void convT64q_k(
    const float* __restrict__ wq, const float* __restrict__ wk,
    const float* __restrict__ wv, bf16* __restrict__ out)
{
    const int z = blockIdx.z;
    const float* in = z == 0 ? wq : (z == 1 ? wk : wv);
    convT64_body(in, out + (size_t)z * DIM * DIM, DIM, DIM, blockIdx.x, blockIdx.y);
}

__global__ __launch_bounds__(256) void convT64f_k(
    const float* __restrict__ w1, const float* __restrict__ w3,
    bf16* __restrict__ o1, bf16* __restrict__ o3)
{
    const int z = blockIdx.z;
    convT64_body(z ? w3 : w1, z ? o3 : o1, DIM, HID, blockIdx.x, blockIdx.y);
}

// ---------------- bf16 transpose with src stride (vt[d][s] = in[s][d]) ----------------
__global__ __launch_bounds__(256) void transpose_bf16_k(
    const bf16* __restrict__ in, int istride, bf16* __restrict__ out)
{
    __shared__ unsigned short t[32][33];
    const int tx = threadIdx.x & 31, ty = threadIdx.x >> 5;
    const int x = blockIdx.x * 32 + tx;
    const int y0 = blockIdx.y * 32;
    const unsigned short* inu = (const unsigned short*)in;
    unsigned short* outu = (unsigned short*)out;
#pragma unroll
    for (int i = 0; i < 4; ++i)
        t[ty + i * 8][tx] = inu[(size_t)(y0 + ty + i * 8) * istride + x];
    __syncthreads();
    const int x2 = blockIdx.y * 32 + tx;
    const int y2 = blockIdx.x * 32;
#pragma unroll
    for (int i = 0; i < 4; ++i)
        outu[(size_t)(y2 + ty + i * 8) * SEQ + x2] = t[tx][ty + i * 8];
}

// ---------------- RoPE in-place, vectorized: 8 elems (4 pairs) per thread ----------------
__global__ __launch_bounds__(256) void rope_qk_k(
    bf16* __restrict__ q, bf16* __restrict__ k,
    const float* __restrict__ cosb, const float* __restrict__ sinb)
{
    const int gid = blockIdx.x * 256 + threadIdx.x;   // < SEQ * 256
    const int s = gid >> 8;
    const int p8 = gid & 255;
    const size_t off = (size_t)s * SQKV + p8 * 8;
    const int j0 = ((p8 * 8) & 127) >> 1;             // 0,4,...,60
    float4 c4 = *(const float4*)(cosb + s * 64 + j0);
    float4 s4 = *(const float4*)(sinb + s * 64 + j0);
    bf16x8 qv = *(const bf16x8*)((const unsigned short*)q + off);
    bf16x8 kv = *(const bf16x8*)((const unsigned short*)k + off);
    bf16x8 qo, ko;
#pragma unroll
    for (int e = 0; e < 4; ++e) {
        const float c = (&c4.x)[e], sn = (&s4.x)[e];
        float xr = bu2f((unsigned short)qv[2 * e]), xi = bu2f((unsigned short)qv[2 * e + 1]);
        qo[2 * e]     = (short)f2bu(xr * c - xi * sn);
        qo[2 * e + 1] = (short)f2bu(xr * sn + xi * c);
        xr = bu2f((unsigned short)kv[2 * e]); xi = bu2f((unsigned short)kv[2 * e + 1]);
        ko[2 * e]     = (short)f2bu(xr * c - xi * sn);
        ko[2 * e + 1] = (short)f2bu(xr * sn + xi * c);
    }
    *(bf16x8*)((unsigned short*)q + off) = qo;
    *(bf16x8*)((unsigned short*)k + off) = ko;
}

// ---------------- 256x256 GEMM, m201 8-phase skeleton, 16x16x32 MFMA, split-K ----------------
// (R17: reverted from 32x32 fragments -- those force a 4-way LDS bank conflict with
//  gl16-staged 128B-row tiles: 32 distinct rows per read vs only 8 swizzle slots.)
// EP 0: store bf16    EP 3: bf16 partial store    EP 4: fused w1|w3 silu-mul
template <int EP>
__global__ __launch_bounds__(512, 1) void gemm256_k(
    const bf16* __restrict__ A, const bf16* __restrict__ Bt, const bf16* __restrict__ Bt2,
    bf16* __restrict__ Cb,
    int M, int N, int K, int gx, int ntile, int Ks)
{
    extern __shared__ char smem[];
    const int t512 = threadIdx.x;
    const int w = t512 >> 6, lane = t512 & 63;
    const int lr = lane & 15, lg = lane >> 4;
    const int wm = w >> 2, wn = w & 3;           // 2 x 4 wave grid
    const int bofs = (wn & 1) * 64;              // B row offset inside its half
    const int swz = (lr & 7) << 4;               // ds_read swizzle

    // XCD-bijective block swizzle (m204)
    const int nwg = gridDim.x;
    const int q8 = nwg >> 3, r8 = nwg & 7;
    const int xcd = blockIdx.x & 7, seqq = blockIdx.x >> 3;
    const int wgid = (xcd < r8 ? xcd * (q8 + 1) : r8 * (q8 + 1) + (xcd - r8) * q8) + seqq;
    const int split = wgid / ntile;
    const int tile = wgid % ntile;
    // GROUP_M=4 supertiling
    const int grp = tile / (4 * gx), rem = tile % (4 * gx);
    const int m0 = (grp * 4 + (rem & 3)) * 256, n0 = (rem >> 2) * 256;
    const int kb0 = split * Ks;
    const int niter = Ks >> 7;

    // staging source pointers (pre-swizzled)
    const bf16* aS[2][2]; const bf16* bS[2][2];
    int sOff[2];
#pragma unroll
    for (int c = 0; c < 2; ++c) {
        const int s = (c * 512 + t512) * 16;
        const int pp = s ^ (((s >> 7) & 7) << 4);
        const int row = pp >> 7, colE = (pp & 127) >> 1;
        sOff[c] = s;
#pragma unroll
        for (int hs = 0; hs < 2; ++hs) {
            aS[hs][c] = A + (size_t)(m0 + hs * 128 + row) * K + kb0 + colE;
            const int rg = n0 + hs * 128 + row;
            if (EP == 4) {
                const int g = rg >> 4;
                const bf16* src = (g & 1) ? Bt2 : Bt;
                const int j = ((g >> 1) << 4) + (rg & 15);
                bS[hs][c] = src + (size_t)j * K + kb0 + colE;
            } else {
                bS[hs][c] = Bt + (size_t)rg * K + kb0 + colE;
            }
        }
    }
    auto stA = [&](int buf, int kt, int hs) {
        char* base = smem + (buf * 2 + hs) * 16384;
        gl16(aS[hs][0] + (kt << 6), base + sOff[0]);
        gl16(aS[hs][1] + (kt << 6), base + sOff[1]);
    };
    auto stB = [&](int buf, int kt, int hs) {
        char* base = smem + 65536 + (buf * 2 + hs) * 16384;
        gl16(bS[hs][0] + (kt << 6), base + sOff[0]);
        gl16(bS[hs][1] + (kt << 6), base + sOff[1]);
    };

    const char* A0m = smem + (0 * 2 + wm) * 16384;
    const char* A1m = smem + (1 * 2 + wm) * 16384;
    const char* B0m = smem + 65536 + (0 * 2 + (wn >> 1)) * 16384;
    const char* B1m = smem + 65536 + (1 * 2 + (wn >> 1)) * 16384;

    f32x4 acc[8][4] = {};
    bf16x8 bfr[4][2];
    bf16x8 x0, x1, x2, x3;

#define SBAR __builtin_amdgcn_s_barrier()
#define LGKM0 do { asm volatile("s_waitcnt lgkmcnt(0)" ::: "memory"); \
                   __builtin_amdgcn_sched_barrier(0); } while (0)
#define WVM(n) do { asm volatile("s_waitcnt vmcnt(" #n ")" ::: "memory"); \
                    __builtin_amdgcn_sched_barrier(0); } while (0)
#define LDA4(base, mf0) do { \
    x0 = *(const bf16x8*)((base) + (((mf0) * 16 + lr) * 128) + ((lg * 16) ^ swz)); \
    x1 = *(const bf16x8*)((base) + (((mf0) * 16 + lr) * 128) + ((64 + lg * 16) ^ swz)); \
    x2 = *(const bf16x8*)((base) + ((((mf0) + 1) * 16 + lr) * 128) + ((lg * 16) ^ swz)); \
    x3 = *(const bf16x8*)((base) + ((((mf0) + 1) * 16 + lr) * 128) + ((64 + lg * 16) ^ swz)); \
    } while (0)
#define LDB8(base) do { \
    _Pragma("unroll") \
    for (int nf = 0; nf < 4; ++nf) { \
        bfr[nf][0] = *(const bf16x8*)((base) + ((bofs + nf * 16 + lr) * 128) + ((lg * 16) ^ swz)); \
        bfr[nf][1] = *(const bf16x8*)((base) + ((bofs + nf * 16 + lr) * 128) + ((64 + lg * 16) ^ swz)); \
    } } while (0)
#define MFMA_PH(mf0) do { \
    __builtin_amdgcn_s_setprio(1); \
    _Pragma("unroll") \
    for (int nf = 0; nf < 4; ++nf) { \
        acc[(mf0)][nf]     = MFMA16(x0, bfr[nf][0], acc[(mf0)][nf]); \
        acc[(mf0)][nf]     = MFMA16(x1, bfr[nf][1], acc[(mf0)][nf]); \
        acc[(mf0) + 1][nf] = MFMA16(x2, bfr[nf][0], acc[(mf0) + 1][nf]); \
        acc[(mf0) + 1][nf] = MFMA16(x3, bfr[nf][1], acc[(mf0) + 1][nf]); \
    } \
    __builtin_amdgcn_s_setprio(0); } while (0)

    // prologue: tile0 B+A (8 gl16), tile1 B (4 gl16); tile1 A staged in iter0 ph1/ph2
    stB(0, 0, 0); stB(0, 0, 1); stA(0, 0, 0); stA(0, 0, 1);
    stB(1, 1, 0); stB(1, 1, 1);
    WVM(4);
    SBAR;

    for (int t = 0; t < niter; ++t) {
        const bool pf = (t + 1 < niter);
        const int k1 = 2 * t + 1, k2 = 2 * t + 2, k3 = 2 * t + 3;

        // ---- ph1 ----
        LDB8(B0m);
        LDA4(A0m, 0);
        stA(1, k1, 0);
        SBAR; LGKM0; MFMA_PH(0); SBAR;
        // ---- ph2 ----
        LDA4(A0m, 2);
        stA(1, k1, 1);
        SBAR; LGKM0; MFMA_PH(2); SBAR;
        // ---- ph3 ----
        LDA4(A0m, 4);
        if (pf) stB(0, k2, 0);
        SBAR; LGKM0; MFMA_PH(4); SBAR;
        // ---- ph4 ----
        if (pf) { WVM(2); } else { WVM(0); }
        LDA4(A0m, 6);
        if (pf) stB(0, k2, 1);
        SBAR; LGKM0; MFMA_PH(6); SBAR;
        // ---- ph5 ----
        LDB8(B1m);
        LDA4(A1m, 0);
        if (pf) stA(0, k2, 0);
        SBAR; LGKM0; MFMA_PH(0); SBAR;
        // ---- ph6 ----
        LDA4(A1m, 2);
        if (pf) stA(0, k2, 1);
        SBAR; LGKM0; MFMA_PH(2); SBAR;
        // ---- ph7 ----
        LDA4(A1m, 4);
        if (pf) stB(1, k3, 0);
        SBAR; LGKM0; MFMA_PH(4); SBAR;
        // ---- ph8 ----
        if (pf) WVM(2);
        LDA4(A1m, 6);
        if (pf) stB(1, k3, 1);
        SBAR; LGKM0; MFMA_PH(6); SBAR;
    }
#undef SBAR
#undef LGKM0
#undef WVM
#undef LDA4
#undef LDB8
#undef MFMA_PH

    // ---- epilogue ----
    if (EP == 4) {
        const int jb = (n0 >> 1) + wn * 32;
        const int NH = N >> 1;                  // = HID
#pragma unroll
        for (int mf = 0; mf < 8; ++mf)
#pragma unroll
            for (int pp = 0; pp < 4; pp += 2) {
                const int row = m0 + wm * 128 + mf * 16 + lg * 4;
                const int j = jb + (pp >> 1) * 16 + lr;
#pragma unroll
                for (int r = 0; r < 4; ++r) {
                    const float a = acc[mf][pp][r];
                    const float b = acc[mf][pp + 1][r];
                    const float s = a / (1.0f + __expf(-a));
                    Cb[(size_t)(row + r) * NH + j] = __float2bfloat16(s * b);
                }
            }
    } else {
        bf16* cb = (EP == 3) ? Cb + (size_t)split * M * N : Cb;
#pragma unroll
        for (int mf = 0; mf < 8; ++mf)
#pragma unroll
            for (int nf = 0; nf < 4; ++nf) {
                const int row = m0 + wm * 128 + mf * 16 + lg * 4;
                const int col = n0 + wn * 64 + nf * 16 + lr;
#pragma unroll
                for (int r = 0; r < 4; ++r)
                    cb[(size_t)(row + r) * N + col] = __float2bfloat16(acc[mf][nf][r]);
            }
    }
}

// ---------------- causal flash attention: paired q-tiles, 8 waves, shared KV ----------------
__global__ __launch_bounds__(512) void attn_fwd_k(
    const bf16* __restrict__ qkv, const bf16* __restrict__ vT, bf16* __restrict__ ctx)
{
    const int tid = threadIdx.x;
    const int w8 = tid >> 6, lane = tid & 63;
    const int lr = lane & 15, lg = lane >> 4;
    const int w = w8 & 3, tsel = w8 >> 2;
    const int h = blockIdx.y;
    const int bx = blockIdx.x;                    // 0..15
    const int qidx = tsel ? (31 - bx) : bx;
    const int q0b = qidx * 64;
    const int myNt = qidx + 1;
    const int nt = 32 - bx;

    __shared__ __align__(16) unsigned short Kt[2][64 * 128];
    __shared__ __align__(16) unsigned short Vt[128 * 64];
    __shared__ __align__(16) unsigned short Pp[8][16 * 64];

    const char* kbase = (const char*)(qkv + DIM + h * HEAD_DIM);
    const char* vbase = (const char*)(vT + (size_t)h * HEAD_DIM * SEQ);

    const int krow_c = tid >> 4;
    const int kcolB  = (tid & 15) * 16;
    const int vrow_c = tid >> 3;
    const int vcolB  = (tid & 7) * 16;

    auto stageK = [&](int buf, int kb) {
#pragma unroll
        for (int c = 0; c < 2; ++c) {
            const int r = c * 32 + krow_c;
            gl16(kbase + (size_t)(kb + r) * (SQKV * 2) + (kcolB ^ ((r & 7) << 4)),
                 &Kt[buf][c * 4096 + tid * 8]);
        }
    };
    auto stageV = [&](int kb) {
#pragma unroll
        for (int c = 0; c < 2; ++c) {
            const int r = c * 64 + vrow_c;
            gl16(vbase + (size_t)r * (SEQ * 2) + kb * 2 + (vcolB ^ ((r & 7) << 4)),
                 &Vt[c * 4096 + tid * 8]);
        }
    };

    bf16x8 qf[4];
    const bf16* qrow = qkv + (size_t)(q0b + w * 16 + lr) * SQKV + h * HEAD_DIM;
#pragma unroll
    for (int dt = 0; dt < 4; ++dt)
        qf[dt] = *(const bf16x8*)(qrow + dt * 32 + lg * 8);

    f32x4 o[8] = {};
    float m[4], l[4];
#pragma unroll
    for (int j = 0; j < 4; ++j) { m[j] = -3e38f; l[j] = 0.0f; }
    const float scale = 0.08838834764831845f;

    stageK(0, 0);
    asm volatile("s_waitcnt vmcnt(0)" ::: "memory");
    __builtin_amdgcn_sched_barrier(0);
    __builtin_amdgcn_s_barrier();

    int cur = 0;
    for (int t = 0; t < nt; ++t) {
        const int kb = t * 64;
        const bool pf = (t + 1 < nt);
        stageV(kb);
        if (pf) stageK(cur ^ 1, kb + 64);
        const bool act = (t < myNt);

        if (act) {
            f32x4 s[4] = {};
            __builtin_amdgcn_s_setprio(1);
#pragma unroll
            for (int ss = 0; ss < 4; ++ss) {
                const int r = ss * 16 + lr;
                const int sw = (r & 7) << 3;
#pragma unroll
                for (int dt = 0; dt < 4; ++dt) {
                    bf16x8 kf = *(const bf16x8*)&Kt[cur][r * 128 + ((dt * 32 + lg * 8) ^ sw)];
                    s[ss] = MFMA16(qf[dt], kf, s[ss]);
                }
            }
            __builtin_amdgcn_s_setprio(0);

            float al[4];
#pragma unroll
            for (int j = 0; j < 4; ++j) {
                const int qi = q0b + w * 16 + lg * 4 + j;
                const int prow = lg * 4 + j;
                const int psw = (prow & 7) << 3;
                float a[4];
#pragma unroll
                for (int ss = 0; ss < 4; ++ss)
                    a[ss] = s[ss][j] * scale + ((kb + ss * 16 + lr) > qi ? -1e9f : 0.0f);
                float mx = fmaxf(fmaxf(a[0], a[1]), fmaxf(a[2], a[3]));
                mx = fmaxf(mx, __shfl_xor(mx, 1));
                mx = fmaxf(mx, __shfl_xor(mx, 2));
                mx = fmaxf(mx, __shfl_xor(mx, 4));
                mx = fmaxf(mx, __shfl_xor(mx, 8));
                const float mn = fmaxf(m[j], mx);
                const float asc = __expf(m[j] - mn);
                float e0 = __expf(a[0] - mn), e1 = __expf(a[1] - mn);
                float e2 = __expf(a[2] - mn), e3 = __expf(a[3] - mn);
                float rs = (e0 + e1) + (e2 + e3);
                rs += __shfl_xor(rs, 1); rs += __shfl_xor(rs, 2);
                rs += __shfl_xor(rs, 4); rs += __shfl_xor(rs, 8);
                l[j] = l[j] * asc + rs;
                m[j] = mn;
                al[j] = asc;
                Pp[w8][prow * 64 + ((lr)      ^ psw)] = f2bu(e0);
                Pp[w8][prow * 64 + ((16 + lr) ^ psw)] = f2bu(e1);
                Pp[w8][prow * 64 + ((32 + lr) ^ psw)] = f2bu(e2);
                Pp[w8][prow * 64 + ((48 + lr) ^ psw)] = f2bu(e3);
            }
#pragma unroll
            for (int d2 = 0; d2 < 8; ++d2)
#pragma unroll
                for (int j = 0; j < 4; ++j) o[d2][j] *= al[j];
        }

        if (pf) { asm volatile("s_waitcnt vmcnt(2)" ::: "memory"); }
        else    { asm volatile("s_waitcnt vmcnt(0)" ::: "memory"); }
        __builtin_amdgcn_sched_barrier(0);
        __builtin_amdgcn_s_barrier();

        if (act) {
            asm volatile("s_waitcnt lgkmcnt(0)" ::: "memory");
            __builtin_amdgcn_sched_barrier(0);
            const int asw = (lr & 7) << 3;
            bf16x8 pa0 = *(const bf16x8*)&Pp[w8][lr * 64 + ((lg * 8)      ^ asw)];
            bf16x8 pa1 = *(const bf16x8*)&Pp[w8][lr * 64 + ((32 + lg * 8) ^ asw)];

            __builtin_amdgcn_s_setprio(1);
#pragma unroll
            for (int d2 = 0; d2 < 8; ++d2) {
                const int rv = d2 * 16 + lr;
                const int vsw = (rv & 7) << 3;
                bf16x8 vf0 = *(const bf16x8*)&Vt[rv * 64 + ((lg * 8)      ^ vsw)];
                bf16x8 vf1 = *(const bf16x8*)&Vt[rv * 64 + ((32 + lg * 8) ^ vsw)];
                o[d2] = MFMA16(pa0, vf0, o[d2]);
                o[d2] = MFMA16(pa1, vf1, o[d2]);
            }
            __builtin_amdgcn_s_setprio(0);
        }

        __builtin_amdgcn_s_barrier();
        cur ^= 1;
    }

#pragma unroll
    for (int j = 0; j < 4; ++j) {
        const float inv = 1.0f / l[j];
        bf16* dst = ctx + (size_t)(q0b + w * 16 + lg * 4 + j) * DIM + h * HEAD_DIM + lr;
#pragma unroll
        for (int d2 = 0; d2 < 8; ++d2)
            dst[d2 * 16] = __float2bfloat16(o[d2][j] * inv);
    }
}

// ---------------- host ----------------
extern "C" void kernel_launch(void* const* d_in, const int* in_sizes, int n_in,
                              void* d_out, int out_size, void* d_ws, size_t ws_size,
                              hipStream_t stream)
{
    const float* x   = (const float*)d_in[0];
    const float* fc  = (const float*)d_in[1];
    const float* fs  = (const float*)d_in[2];
    // d_in[3] = mask (unused; causal computed analytically)
    const float* wq  = (const float*)d_in[4];
    const float* wk  = (const float*)d_in[5];
    const float* wv  = (const float*)d_in[6];
    const float* wo  = (const float*)d_in[7];
    const float* w1  = (const float*)d_in[8];
    const float* w2  = (const float*)d_in[9];
    const float* w3  = (const float*)d_in[10];
    const float* anw = (const float*)d_in[11];
    const float* fnw = (const float*)d_in[12];
    float* out = (float*)d_out;

    char* p = (char*)d_ws;
    auto alloc = [&](size_t n) { char* r = p; p += (n + 255) & ~(size_t)255; return r; };
    bf16* wT  = (bf16*)alloc((size_t)HID * DIM * 2);
    bf16* hn  = (bf16*)alloc((size_t)SEQ * DIM * 2);     // dead after QKV GEMM
    bf16* qkv = (bf16*)alloc((size_t)SEQ * SQKV * 2);    // dead after attn
    bf16* vt  = (bf16*)alloc((size_t)SEQ * DIM * 2);
    bf16* ctx = (bf16*)alloc((size_t)SEQ * DIM * 2);
    bf16* fn  = (bf16*)alloc((size_t)SEQ * DIM * 2);
    float* h  = (float*)alloc((size_t)SEQ * DIM * 4);
    bf16* g   = (bf16*)alloc((size_t)SEQ * HID * 2);
    bf16* sk  = (bf16*)alloc((size_t)4 * SEQ * DIM * 2);
    bf16* w3T = hn;   // aliases hn+qkv (dead by then)

    const int LDS256 = 131072;
    (void)hipFuncSetAttribute((const void*)gemm256_k<0>,
        hipFuncAttributeMaxDynamicSharedMemorySize, LDS256);
    (void)hipFuncSetAttribute((const void*)gemm256_k<3>,
        hipFuncAttributeMaxDynamicSharedMemorySize, LDS256);
    (void)hipFuncSetAttribute((const void*)gemm256_k<4>,
        hipFuncAttributeMaxDynamicSharedMemorySize, LDS256);

    rmsnorm_bf16_k<<<SEQ, 256, 0, stream>>>(x, anw, hn);

    convT64q_k<<<dim3(DIM / 64, DIM / 64, 3), 256, 0, stream>>>(wq, wk, wv, wT);
    gemm256_k<0><<<(SEQ / 256) * (SQKV / 256), 512, LDS256, stream>>>(
        hn, wT, nullptr, qkv, SEQ, SQKV, DIM, SQKV / 256, (SEQ / 256) * (SQKV / 256), DIM);

    rope_qk_k<<<(SEQ * 256) / 256, 256, 0, stream>>>(qkv, qkv + DIM, fc, fs);
    transpose_bf16_k<<<dim3(DIM / 32, SEQ / 32), 256, 0, stream>>>(qkv + 2 * DIM, SQKV, vt);

    attn_fwd_k<<<dim3(16, N_HEADS), 512, 0, stream>>>(qkv, vt, ctx);

    convT64_k<<<dim3(DIM / 64, DIM / 64), 256, 0, stream>>>(wo, wT, DIM, DIM);
    gemm256_k<3><<<(SEQ / 256) * (DIM / 256) * 4, 512, LDS256, stream>>>(
        ctx, wT, nullptr, sk, SEQ, DIM, DIM, DIM / 256, (SEQ / 256) * (DIM / 256), 512);
    rmsnorm4_k<<<SEQ, 256, 0, stream>>>(sk, x, fnw, h, fn);

    convT64f_k<<<dim3(HID / 64, DIM / 64, 2), 256, 0, stream>>>(w1, w3, wT, w3T);
    gemm256_k<4><<<(SEQ / 256) * ((2 * HID) / 256), 512, LDS256, stream>>>(
        fn, wT, w3T, g, SEQ, 2 * HID, DIM, (2 * HID) / 256,
        (SEQ / 256) * ((2 * HID) / 256), DIM);

    convT64_k<<<dim3(DIM / 64, HID / 64), 256, 0, stream>>>(w2, wT, HID, DIM);
    gemm256_k<3><<<(SEQ / 256) * (DIM / 256) * 4, 512, LDS256, stream>>>(
        g, wT, nullptr, sk, SEQ, DIM, HID, DIM / 256, (SEQ / 256) * (DIM / 256), 2048);
    reduce4_k<<<(SEQ * DIM / 8) / 256, 256, 0, stream>>>(sk, h, out);
}